// Round 10
// baseline (3119.574 us; speedup 1.0000x reference)
//
#include <hip/hip_runtime.h>

#define BB 64
#define TT 512
#define EE 128
#define HH 512
#define NGRP 4
#define BG 16
#define JW 16
#define NSLOT 132
#define LDH 520   // 512 + 8 fp16 pad
#define LDE 136   // 128 + 8

typedef _Float16 f16;
typedef f16 f16x8 __attribute__((ext_vector_type(8)));
typedef float floatx4 __attribute__((ext_vector_type(4)));
typedef unsigned u32x4 __attribute__((ext_vector_type(4)));
typedef unsigned long long u64;

__device__ __forceinline__ float sigmf(float x) { return 1.f / (1.f + __expf(-x)); }
__device__ __forceinline__ float tanhfast(float x) { return 2.f / (1.f + __expf(-2.f * x)) - 1.f; }

// ---------------- slot map ----------------
__global__ __launch_bounds__(64) void build_map(const int* __restrict__ bnd,
                                                int* __restrict__ slotmap)
{
  __shared__ unsigned char need[TT];
  const int b = blockIdx.x;
  for (int i = threadIdx.x; i < TT; i += 64) need[i] = 0;
  __syncthreads();
  {
    const int w = threadIdx.x;
    const int iv = bnd[b * 65 + w];
    const int jv = bnd[b * 65 + w + 1];
    if (iv != -1 && jv != -1) {
      int ic = iv < 0 ? 0 : (iv > TT - 1 ? TT - 1 : iv);
      int jc = jv < 0 ? 0 : (jv > TT - 1 ? TT - 1 : jv);
      need[ic] = 1;
      need[jc] = 1;
    }
  }
  __syncthreads();
  if (threadIdx.x == 0) {
    int c = 0;
    for (int t = 0; t < TT; ++t) slotmap[b * TT + t] = need[t] ? (c++) : -1;
  }
}

// ---------------- persistent bidirectional LSTM scan ----------------
// 256 blocks x 256 threads; domain = blockIdx&7 = (dir,grp), 32 slice-blocks.
// h exchange: u32 = (step_tag<<16)|f16_bits, sc1 fire-and-forget stores;
// consumers issue all loads, overlap x-MFMAs, validate tags, batched retry.
// Per-lane direct register export; masks/slots in registers; 2 barriers/step.
__global__ __launch_bounds__(256, 1) void lstm_scan(
    const int* __restrict__ ids, const int* __restrict__ maskI,
    const float* __restrict__ emb,
    const float* __restrict__ Wih_f, const float* __restrict__ Whh_f, const float* __restrict__ b_f,
    const float* __restrict__ Wih_b, const float* __restrict__ Whh_b, const float* __restrict__ b_b,
    const int* __restrict__ slotmap,
    unsigned* __restrict__ h_g,   // [2 buf][2 dir][NGRP][BG][HH] u32 (tag|f16)
    f16* __restrict__ hist)       // [2 dir][BB][NSLOT][HH] f16
{
  __shared__ f16 sH[BG * LDH];
  __shared__ f16 sX[BG * LDE];

  const int tid = threadIdx.x;
  const int bid = blockIdx.x;
  const int dom = bid & 7;
  const int slice = bid >> 3;          // 0..31
  const int dir = dom & 1;
  const int grp = dom >> 1;

  const float* Wih = dir ? Wih_b : Wih_f;
  const float* Whh = dir ? Whh_b : Whh_f;
  const float* bv  = dir ? b_b   : b_f;

  const int lane = tid & 63;
  const int wave = tid >> 6;
  const int rloc = lane & 15;
  const int kg   = lane >> 4;
  const int rglob = wave * 16 + rloc;  // gate-row in slice, r = jloc*4 + q
  const int jloc  = rglob >> 2;
  const int q     = rglob & 3;         // 0=i,1=f,2=g,3=o
  const int mbase = kg * 4;
  const int growL = q * HH + slice * JW + jloc;
  const int gb = grp * BG;             // batch group base (global)
  const int expb = gb + mbase + q;     // this lane's export batch (global)

  // --- preload step-invariant weights into registers (fp32 -> fp16) ---
  f16x8 wh[16];
  {
    const float* wr = Whh + (size_t)growL * HH + kg * 8;
    #pragma unroll
    for (int kk = 0; kk < 16; ++kk) {
      float4 a0 = *(const float4*)(wr + kk * 32);
      float4 a1 = *(const float4*)(wr + kk * 32 + 4);
      f16x8 v;
      v[0]=(f16)a0.x; v[1]=(f16)a0.y; v[2]=(f16)a0.z; v[3]=(f16)a0.w;
      v[4]=(f16)a1.x; v[5]=(f16)a1.y; v[6]=(f16)a1.z; v[7]=(f16)a1.w;
      wh[kk] = v;
    }
  }
  f16x8 wx[4];
  {
    const float* wr = Wih + (size_t)growL * EE + kg * 8;
    #pragma unroll
    for (int kk = 0; kk < 4; ++kk) {
      float4 a0 = *(const float4*)(wr + kk * 32);
      float4 a1 = *(const float4*)(wr + kk * 32 + 4);
      f16x8 v;
      v[0]=(f16)a0.x; v[1]=(f16)a0.y; v[2]=(f16)a0.z; v[3]=(f16)a0.w;
      v[4]=(f16)a1.x; v[5]=(f16)a1.y; v[6]=(f16)a1.z; v[7]=(f16)a1.w;
      wx[kk] = v;
    }
  }
  const float bsc = bv[growL];

  float cc[4] = {0.f, 0.f, 0.f, 0.f};
  float hh[4] = {0.f, 0.f, 0.f, 0.f};
  int budget = 1000000;                // retry-ROUND watchdog: fast-fail, never hang

  const int xrow = tid >> 4;           // x staging: batch row
  const int xc0 = (tid & 15) * 8;      // x staging: col base

  // ---- prologue: regs for s=0, zero sH, stage x(t0) ----
  float m4c[4]; int slotC;
  {
    const int t0 = dir ? (TT - 1) : 0;
    #pragma unroll
    for (int i = 0; i < 4; ++i)
      m4c[i] = (float)maskI[(gb + mbase + i) * TT + t0];
    slotC = slotmap[expb * TT + t0];
    for (int e = tid; e < BG * LDH / 2; e += 256) ((unsigned*)sH)[e] = 0u;
    const int b0 = gb + xrow;
    const int idx0 = ids[b0 * TT + t0];
    float4 x0 = *(const float4*)(emb + (size_t)idx0 * EE + xc0);
    float4 x1 = *(const float4*)(emb + (size_t)idx0 * EE + xc0 + 4);
    f16x8 xv;
    xv[0]=(f16)x0.x; xv[1]=(f16)x0.y; xv[2]=(f16)x0.z; xv[3]=(f16)x0.w;
    xv[4]=(f16)x1.x; xv[5]=(f16)x1.y; xv[6]=(f16)x1.z; xv[7]=(f16)x1.w;
    *(f16x8*)(sX + xrow * LDE + xc0) = xv;
  }
  __syncthreads();

  for (int s = 0; s < TT; ++s) {
    unsigned* hq = h_g + (((size_t)(s & 1) * 2 + dir) * NGRP + grp) * BG * HH;
    u32x4 pre[8];
    // ---- issue all 8 tagged h loads (in flight across x work) ----
    if (s > 0) {
      #pragma unroll
      for (int p = 0; p < 8; ++p)
        asm volatile("global_load_dwordx4 %0, %1, off sc1"
                     : "=v"(pre[p]) : "v"(hq + p * 1024 + tid * 4) : "memory");
    }

    // ---- prefetch x/mask/slot for s+1 into registers ----
    const int ns = s + 1;
    float4 px0, px1; float m4n[4] = {0.f, 0.f, 0.f, 0.f}; int slotN = -1;
    if (ns < TT) {
      const int tn = dir ? (TT - 1 - ns) : ns;
      const int bx = gb + xrow;
      const int idx = ids[bx * TT + tn];
      px0 = *(const float4*)(emb + (size_t)idx * EE + xc0);
      px1 = *(const float4*)(emb + (size_t)idx * EE + xc0 + 4);
      #pragma unroll
      for (int i = 0; i < 4; ++i)
        m4n[i] = (float)maskI[(gb + mbase + i) * TT + tn];
      slotN = slotmap[expb * TT + tn];
    }

    // ---- x-part MFMAs (independent of h; overlaps the load RT) ----
    floatx4 acc0 = {0.f, 0.f, 0.f, 0.f};
    floatx4 acc1 = {0.f, 0.f, 0.f, 0.f};
    {
      const f16* aX = sX + rloc * LDE + kg * 8;
      f16x8 a0 = *(const f16x8*)(aX + 0 * 32);
      f16x8 a1 = *(const f16x8*)(aX + 1 * 32);
      f16x8 a2 = *(const f16x8*)(aX + 2 * 32);
      f16x8 a3 = *(const f16x8*)(aX + 3 * 32);
      acc0 = __builtin_amdgcn_mfma_f32_16x16x32_f16(a0, wx[0], acc0, 0, 0, 0);
      acc1 = __builtin_amdgcn_mfma_f32_16x16x32_f16(a1, wx[1], acc1, 0, 0, 0);
      acc0 = __builtin_amdgcn_mfma_f32_16x16x32_f16(a2, wx[2], acc0, 0, 0, 0);
      acc1 = __builtin_amdgcn_mfma_f32_16x16x32_f16(a3, wx[3], acc1, 0, 0, 0);
    }

    // ---- wait, validate tags, BATCHED retry, scatter to sH ----
    if (s > 0) {
      const unsigned tagrep = (unsigned)s << 16;
      asm volatile("s_waitcnt vmcnt(0)" ::: "memory");
      __builtin_amdgcn_sched_barrier(0);
      unsigned bad = 0;
      #pragma unroll
      for (int p = 0; p < 8; ++p) {
        const unsigned d = ((pre[p][0] ^ tagrep) | (pre[p][1] ^ tagrep) |
                           (pre[p][2] ^ tagrep) | (pre[p][3] ^ tagrep)) & 0xffff0000u;
        bad |= (d ? 1u : 0u) << p;
      }
      while (__builtin_expect(bad != 0, 0)) {
        if (--budget < 0) break;
        #pragma unroll
        for (int p = 0; p < 8; ++p)
          if (bad & (1u << p))
            asm volatile("global_load_dwordx4 %0, %1, off sc1"
                         : "=v"(pre[p]) : "v"(hq + p * 1024 + tid * 4) : "memory");
        asm volatile("s_waitcnt vmcnt(0)" ::: "memory");
        unsigned nb = 0;
        #pragma unroll
        for (int p = 0; p < 8; ++p) {
          const unsigned d = ((pre[p][0] ^ tagrep) | (pre[p][1] ^ tagrep) |
                             (pre[p][2] ^ tagrep) | (pre[p][3] ^ tagrep)) & 0xffff0000u;
          nb |= (d ? 1u : 0u) << p;
        }
        bad = nb;
      }
      __builtin_amdgcn_sched_barrier(0);
      #pragma unroll
      for (int p = 0; p < 8; ++p) {
        const unsigned lo = (pre[p][0] & 0xffffu) | (pre[p][1] << 16);
        const unsigned hi = (pre[p][2] & 0xffffu) | (pre[p][3] << 16);
        const int i0 = p * 1024 + tid * 4;        // f16 index in [16][512]
        *(u64*)(sH + (i0 >> 9) * LDH + (i0 & 511)) = ((u64)hi << 32) | lo;
      }
    }
    __syncthreads();                   // B1: sH staged before h-MFMA reads

    // ---- h-part MFMAs ----
    {
      const f16* aH = sH + rloc * LDH + kg * 8;
      #pragma unroll
      for (int kk = 0; kk < 16; kk += 2) {
        f16x8 a0 = *(const f16x8*)(aH + kk * 32);
        f16x8 a1 = *(const f16x8*)(aH + (kk + 1) * 32);
        acc0 = __builtin_amdgcn_mfma_f32_16x16x32_f16(a0, wh[kk], acc0, 0, 0, 0);
        acc1 = __builtin_amdgcn_mfma_f32_16x16x32_f16(a1, wh[kk + 1], acc1, 0, 0, 0);
      }
    }
    floatx4 acc = acc0 + acc1;

    // ---- commit x for s+1 (readers of sX[s] all completed before B1) ----
    if (ns < TT) {
      f16x8 xv;
      xv[0]=(f16)px0.x; xv[1]=(f16)px0.y; xv[2]=(f16)px0.z; xv[3]=(f16)px0.w;
      xv[4]=(f16)px1.x; xv[5]=(f16)px1.y; xv[6]=(f16)px1.z; xv[7]=(f16)px1.w;
      *(f16x8*)(sX + xrow * LDE + xc0) = xv;
    }
    __syncthreads();                   // B2: sH reads + sX commit drained

    // ---- epilogue: quad-exchange gate types, LSTM cell update ----
    #pragma unroll
    for (int i = 0; i < 4; ++i) {
      const float g0 = acc[i] + bsc;
      const float s1 = __shfl_xor(g0, 1, 64);
      const float s2 = __shfl_xor(g0, 2, 64);
      const float s3 = __shfl_xor(s1, 2, 64);
      float vi, vf, vg, vo;
      if (q == 0)      { vi = g0; vf = s1; vg = s2; vo = s3; }
      else if (q == 1) { vi = s1; vf = g0; vg = s3; vo = s2; }
      else if (q == 2) { vi = s2; vf = s3; vg = g0; vo = s1; }
      else             { vi = s3; vf = s2; vg = s1; vo = g0; }
      const float ig = sigmf(vi);
      const float fg = sigmf(vf);
      const float gt = tanhfast(vg);
      const float og = sigmf(vo);
      const float cn = fg * cc[i] + ig * gt;
      const float hn = og * tanhfast(cn);
      const float m = m4c[i];
      cc[i] = m > 0.f ? cn : cc[i];
      float hk = m > 0.f ? hn : hh[i];
      const f16 h16 = (f16)hk;          // round state to fp16 so all consumers agree
      hh[i] = (float)h16;
    }

    // ---- per-lane direct export (batch mbase+q, col jloc) ----
    {
      const float hqv = (q == 0) ? hh[0] : (q == 1) ? hh[1] : (q == 2) ? hh[2] : hh[3];
      const float mq  = (q == 0) ? m4c[0] : (q == 1) ? m4c[1] : (q == 2) ? m4c[2] : m4c[3];
      const f16 h16q = (f16)hqv;
      unsigned short hb; __builtin_memcpy(&hb, &h16q, 2);
      if (ns < TT) {
        const unsigned ev = ((unsigned)ns << 16) | (unsigned)hb;
        unsigned* hdst = h_g + (((size_t)(ns & 1) * 2 + dir) * NGRP + grp) * BG * HH
                         + (mbase + q) * HH + slice * JW + jloc;
        asm volatile("global_store_dword %0, %1, off sc1" :: "v"(hdst), "v"(ev) : "memory");
      }
      if (slotC >= 0) {
        const f16 hv = mq > 0.f ? h16q : (f16)0.f;   // ys = h * m
        hist[((size_t)(dir * BB + expb) * NSLOT + slotC) * HH + slice * JW + jloc] = hv;
      }
    }

    // ---- rotate per-step registers ----
    #pragma unroll
    for (int i = 0; i < 4; ++i) m4c[i] = m4n[i];
    slotC = slotN;
  }
}

// ---------------- gather boundary outputs ----------------
__global__ __launch_bounds__(256) void gather_out(
    const int* __restrict__ bnd, const int* __restrict__ slotmap,
    const f16* __restrict__ hist, float* __restrict__ out)
{
  const int bw = blockIdx.x;
  const int b = bw >> 6;
  const int w = bw & 63;
  const int k = threadIdx.x * 8;
  const int iv = bnd[b * 65 + w];
  const int jv = bnd[b * 65 + w + 1];
  const bool valid = (iv != -1) && (jv != -1);
  float* dst = out + (size_t)bw * 2048 + k;
  if (valid) {
    const int seg = k >> 9;                    // 0:h_f(i) 1:h_b(i) 2:h_f(j) 3:h_b(j)
    int ts = (seg < 2) ? iv : jv;
    ts = ts < 0 ? 0 : (ts > TT - 1 ? TT - 1 : ts);
    const int dirn = seg & 1;
    const int slot = slotmap[b * TT + ts];
    const f16* src = hist + ((size_t)(dirn * BB + b) * NSLOT + slot) * HH + (k & 511);
    f16x8 v = *(const f16x8*)src;
    float4 o0 = make_float4((float)v[0], (float)v[1], (float)v[2], (float)v[3]);
    float4 o1 = make_float4((float)v[4], (float)v[5], (float)v[6], (float)v[7]);
    *(float4*)dst = o0;
    *(float4*)(dst + 4) = o1;
  } else {
    float4 z = make_float4(0.f, 0.f, 0.f, 0.f);
    *(float4*)dst = z;
    *(float4*)(dst + 4) = z;
  }
}

extern "C" void kernel_launch(void* const* d_in, const int* in_sizes, int n_in,
                              void* d_out, int out_size, void* d_ws, size_t ws_size,
                              hipStream_t stream)
{
  (void)in_sizes; (void)n_in; (void)out_size; (void)ws_size;
  const int* ids     = (const int*)d_in[0];
  const int* maskI   = (const int*)d_in[1];
  const int* bnd     = (const int*)d_in[2];
  const float* emb   = (const float*)d_in[3];
  const float* Wih_f = (const float*)d_in[4];
  const float* Whh_f = (const float*)d_in[5];
  const float* b_f   = (const float*)d_in[6];
  const float* Wih_b = (const float*)d_in[7];
  const float* Whh_b = (const float*)d_in[8];
  const float* b_b   = (const float*)d_in[9];

  char* ws = (char*)d_ws;
  int* slotmap    = (int*)ws;                          // 128 KiB
  unsigned* h_g   = (unsigned*)(ws + 131072);          // 2*2*4*16*512*4 = 1 MiB
  f16* hist       = (f16*)(ws + 131072 + 1048576);     // ~16.5 MiB

  hipMemsetAsync(h_g, 0, 1048576, stream);             // tags := 0 (expected 1..511)
  build_map<<<dim3(BB), dim3(64), 0, stream>>>(bnd, slotmap);
  lstm_scan<<<dim3(256), dim3(256), 0, stream>>>(ids, maskI, emb,
      Wih_f, Whh_f, b_f, Wih_b, Whh_b, b_b, slotmap, h_g, hist);
  gather_out<<<dim3(BB * 64), dim3(256), 0, stream>>>(bnd, slotmap, hist, (float*)d_out);
}

// Round 11
// 1898.618 us; speedup vs baseline: 1.6431x; 1.6431x over previous
//
#include <hip/hip_runtime.h>

#define BB 64
#define TT 512
#define EE 128
#define HH 512
#define NGRP 4
#define BG 16
#define JW 16
#define NSLOT 132
#define LDH 520   // 512 + 8 fp16 pad
#define LDE 136   // 128 + 8

typedef _Float16 f16;
typedef f16 f16x8 __attribute__((ext_vector_type(8)));
typedef float floatx4 __attribute__((ext_vector_type(4)));
typedef unsigned u32x4 __attribute__((ext_vector_type(4)));
typedef unsigned long long u64;

__device__ __forceinline__ float sigmf(float x) { return 1.f / (1.f + __expf(-x)); }
__device__ __forceinline__ float tanhfast(float x) { return 2.f / (1.f + __expf(-2.f * x)) - 1.f; }

// ---------------- slot map ----------------
__global__ __launch_bounds__(64) void build_map(const int* __restrict__ bnd,
                                                int* __restrict__ slotmap)
{
  __shared__ unsigned char need[TT];
  const int b = blockIdx.x;
  for (int i = threadIdx.x; i < TT; i += 64) need[i] = 0;
  __syncthreads();
  {
    const int w = threadIdx.x;
    const int iv = bnd[b * 65 + w];
    const int jv = bnd[b * 65 + w + 1];
    if (iv != -1 && jv != -1) {
      int ic = iv < 0 ? 0 : (iv > TT - 1 ? TT - 1 : iv);
      int jc = jv < 0 ? 0 : (jv > TT - 1 ? TT - 1 : jv);
      need[ic] = 1;
      need[jc] = 1;
    }
  }
  __syncthreads();
  if (threadIdx.x == 0) {
    int c = 0;
    for (int t = 0; t < TT; ++t) slotmap[b * TT + t] = need[t] ? (c++) : -1;
  }
}

// ---------------- persistent bidirectional LSTM scan ----------------
// 256 blocks x 256 threads; domain = blockIdx&7 = (dir,grp), 32 slice-blocks.
// R3's proven flag barrier (agent/L3), with: batched one-waitcnt staging loads
// overlapped with x-MFMAs, unchained x prefetch pipeline, hist off the drain,
// 2 barriers/step.
__global__ __launch_bounds__(256, 1) void lstm_scan(
    const int* __restrict__ ids, const int* __restrict__ maskI,
    const float* __restrict__ emb,
    const float* __restrict__ Wih_f, const float* __restrict__ Whh_f, const float* __restrict__ b_f,
    const float* __restrict__ Wih_b, const float* __restrict__ Whh_b, const float* __restrict__ b_b,
    const int* __restrict__ slotmap,
    f16* __restrict__ h_g,        // [2 buf][2 dir][NGRP][BG][HH] fp16 ping-pong
    f16* __restrict__ hist,       // [2 dir][BB][NSLOT][HH] fp16
    unsigned* __restrict__ flags) // [8][32] step flags (one 128B line per domain)
{
  __shared__ f16 sH[BG * LDH];
  __shared__ f16 sX[BG * LDE];
  __shared__ f16 hOut[BG * JW];

  const int tid = threadIdx.x;
  const int bid = blockIdx.x;
  const int dom = bid & 7;
  const int slice = bid >> 3;          // 0..31
  const int dir = dom & 1;
  const int grp = dom >> 1;

  const float* Wih = dir ? Wih_b : Wih_f;
  const float* Whh = dir ? Whh_b : Whh_f;
  const float* bv  = dir ? b_b   : b_f;

  const int lane = tid & 63;
  const int wave = tid >> 6;
  const int rloc = lane & 15;
  const int kg   = lane >> 4;
  const int rglob = wave * 16 + rloc;  // gate-row in slice, r = jloc*4 + q
  const int jloc  = rglob >> 2;
  const int q     = rglob & 3;         // 0=i,1=f,2=g,3=o
  const int mbase = kg * 4;
  const int growL = q * HH + slice * JW + jloc;
  const int gb = grp * BG;             // batch group base
  const int blw = tid >> 2;            // wave0 export batch (tid<64)

  // --- preload step-invariant weights into registers (fp32 -> fp16) ---
  f16x8 wh[16];
  {
    const float* wr = Whh + (size_t)growL * HH + kg * 8;
    #pragma unroll
    for (int kk = 0; kk < 16; ++kk) {
      float4 a0 = *(const float4*)(wr + kk * 32);
      float4 a1 = *(const float4*)(wr + kk * 32 + 4);
      f16x8 v;
      v[0]=(f16)a0.x; v[1]=(f16)a0.y; v[2]=(f16)a0.z; v[3]=(f16)a0.w;
      v[4]=(f16)a1.x; v[5]=(f16)a1.y; v[6]=(f16)a1.z; v[7]=(f16)a1.w;
      wh[kk] = v;
    }
  }
  f16x8 wx[4];
  {
    const float* wr = Wih + (size_t)growL * EE + kg * 8;
    #pragma unroll
    for (int kk = 0; kk < 4; ++kk) {
      float4 a0 = *(const float4*)(wr + kk * 32);
      float4 a1 = *(const float4*)(wr + kk * 32 + 4);
      f16x8 v;
      v[0]=(f16)a0.x; v[1]=(f16)a0.y; v[2]=(f16)a0.z; v[3]=(f16)a0.w;
      v[4]=(f16)a1.x; v[5]=(f16)a1.y; v[6]=(f16)a1.z; v[7]=(f16)a1.w;
      wx[kk] = v;
    }
  }
  const float bsc = bv[growL];

  float cc[4] = {0.f, 0.f, 0.f, 0.f};
  float hh[4] = {0.f, 0.f, 0.f, 0.f};
  int wd = 3000000;                    // poll watchdog: fast-fail, never hang

  const int xrow = tid >> 4;           // x staging: batch row
  const int xc0 = (tid & 15) * 8;      // x staging: col base

  // ---- prologue: regs for t0, idx pipeline, zero sH, stage x(t0) ----
  float m4c[4]; float mBc = 0.f; int slotBc = -1; int idxN = 0;
  {
    const int t0 = dir ? (TT - 1) : 0;
    #pragma unroll
    for (int i = 0; i < 4; ++i)
      m4c[i] = (float)maskI[(gb + mbase + i) * TT + t0];
    if (tid < 64) {
      mBc = (float)maskI[(gb + blw) * TT + t0];
      slotBc = slotmap[(gb + blw) * TT + t0];
    }
    idxN = ids[(gb + xrow) * TT + (dir ? (TT - 2) : 1)];
    for (int e = tid; e < BG * 64; e += 256) {
      const int row = e >> 6, ch = e & 63;
      uint4 z = make_uint4(0u, 0u, 0u, 0u);
      *(uint4*)(sH + row * LDH + ch * 8) = z;
    }
    const int idx0 = ids[(gb + xrow) * TT + t0];
    float4 x0 = *(const float4*)(emb + (size_t)idx0 * EE + xc0);
    float4 x1 = *(const float4*)(emb + (size_t)idx0 * EE + xc0 + 4);
    f16x8 xv;
    xv[0]=(f16)x0.x; xv[1]=(f16)x0.y; xv[2]=(f16)x0.z; xv[3]=(f16)x0.w;
    xv[4]=(f16)x1.x; xv[5]=(f16)x1.y; xv[6]=(f16)x1.z; xv[7]=(f16)x1.w;
    *(f16x8*)(sX + xrow * LDE + xc0) = xv;
  }
  __syncthreads();

  for (int s = 0; s < TT; ++s) {
    const int ns = s + 1;

    // ---- 1. issue batched h loads (4 x dwordx4 sc1, in flight) ----
    u32x4 hv[4];
    if (s > 0) {
      const f16* hq = h_g + (((size_t)(s & 1) * 2 + dir) * NGRP + grp) * BG * HH;
      #pragma unroll
      for (int p = 0; p < 4; ++p)
        asm volatile("global_load_dwordx4 %0, %1, off sc1"
                     : "=v"(hv[p]) : "v"(hq + (size_t)(p * 256 + tid) * 8) : "memory");
    }

    // ---- 2. prefetch x/mask/slot for ns (all loads independent) ----
    float4 px0, px1; float m4n[4] = {0.f,0.f,0.f,0.f}; float mBn = 0.f; int slotBn = -1;
    const int idxC = idxN;
    if (ns < TT) {
      const int tn = dir ? (TT - 1 - ns) : ns;
      if (ns + 1 < TT) idxN = ids[(gb + xrow) * TT + (dir ? (TT - 2 - ns) : (ns + 1))];
      px0 = *(const float4*)(emb + (size_t)idxC * EE + xc0);
      px1 = *(const float4*)(emb + (size_t)idxC * EE + xc0 + 4);
      #pragma unroll
      for (int i = 0; i < 4; ++i)
        m4n[i] = (float)maskI[(gb + mbase + i) * TT + tn];
      if (tid < 64) {
        mBn = (float)maskI[(gb + blw) * TT + tn];
        slotBn = slotmap[(gb + blw) * TT + tn];
      }
    }

    // ---- 3. x-part MFMAs (overlap the h-load RT) ----
    floatx4 acc0 = {0.f, 0.f, 0.f, 0.f};
    floatx4 acc1 = {0.f, 0.f, 0.f, 0.f};
    {
      const f16* aX = sX + rloc * LDE + kg * 8;
      f16x8 a0 = *(const f16x8*)(aX + 0 * 32);
      f16x8 a1 = *(const f16x8*)(aX + 1 * 32);
      f16x8 a2 = *(const f16x8*)(aX + 2 * 32);
      f16x8 a3 = *(const f16x8*)(aX + 3 * 32);
      acc0 = __builtin_amdgcn_mfma_f32_16x16x32_f16(a0, wx[0], acc0, 0, 0, 0);
      acc1 = __builtin_amdgcn_mfma_f32_16x16x32_f16(a1, wx[1], acc1, 0, 0, 0);
      acc0 = __builtin_amdgcn_mfma_f32_16x16x32_f16(a2, wx[2], acc0, 0, 0, 0);
      acc1 = __builtin_amdgcn_mfma_f32_16x16x32_f16(a3, wx[3], acc1, 0, 0, 0);
    }

    // ---- 4/5. single wait, scatter h to sH (lane-consecutive 16B) ----
    if (s > 0) {
      asm volatile("s_waitcnt vmcnt(0)" ::: "memory");
      __builtin_amdgcn_sched_barrier(0);
      #pragma unroll
      for (int p = 0; p < 4; ++p) {
        const int e = p * 256 + tid;       // 16B chunk; 64 per 512-f16 row
        const int row = e >> 6, ch = e & 63;
        *(u32x4*)(sH + row * LDH + ch * 8) = hv[p];
      }
    }
    __syncthreads();                       // B1: sH staged; all sX reads done

    // ---- 7. commit x for ns ----
    if (ns < TT) {
      f16x8 xv;
      xv[0]=(f16)px0.x; xv[1]=(f16)px0.y; xv[2]=(f16)px0.z; xv[3]=(f16)px0.w;
      xv[4]=(f16)px1.x; xv[5]=(f16)px1.y; xv[6]=(f16)px1.z; xv[7]=(f16)px1.w;
      *(f16x8*)(sX + xrow * LDE + xc0) = xv;
    }

    // ---- 8. h-part MFMAs ----
    {
      const f16* aH = sH + rloc * LDH + kg * 8;
      #pragma unroll
      for (int kk = 0; kk < 16; kk += 2) {
        f16x8 a0 = *(const f16x8*)(aH + kk * 32);
        f16x8 a1 = *(const f16x8*)(aH + (kk + 1) * 32);
        acc0 = __builtin_amdgcn_mfma_f32_16x16x32_f16(a0, wh[kk], acc0, 0, 0, 0);
        acc1 = __builtin_amdgcn_mfma_f32_16x16x32_f16(a1, wh[kk + 1], acc1, 0, 0, 0);
      }
    }
    floatx4 acc = acc0 + acc1;

    // ---- 9. epilogue: quad-exchange gate types, LSTM cell update ----
    #pragma unroll
    for (int i = 0; i < 4; ++i) {
      const float g0 = acc[i] + bsc;
      const float s1 = __shfl_xor(g0, 1, 64);
      const float s2 = __shfl_xor(g0, 2, 64);
      const float s3 = __shfl_xor(s1, 2, 64);
      float vi, vf, vg, vo;
      if (q == 0)      { vi = g0; vf = s1; vg = s2; vo = s3; }
      else if (q == 1) { vi = s1; vf = g0; vg = s3; vo = s2; }
      else if (q == 2) { vi = s2; vf = s3; vg = g0; vo = s1; }
      else             { vi = s3; vf = s2; vg = s1; vo = g0; }
      const float ig = sigmf(vi);
      const float fg = sigmf(vf);
      const float gt = tanhfast(vg);
      const float og = sigmf(vo);
      const float cn = fg * cc[i] + ig * gt;
      const float hn = og * tanhfast(cn);
      const float m = m4c[i];
      cc[i] = m > 0.f ? cn : cc[i];
      float hk = m > 0.f ? hn : hh[i];
      const f16 h16 = (f16)hk;             // round state to fp16 so all consumers agree
      hh[i] = (float)h16;
    }
    {
      const float hq_ = (q == 0) ? hh[0] : (q == 1) ? hh[1] : (q == 2) ? hh[2] : hh[3];
      hOut[(mbase + q) * JW + jloc] = (f16)hq_;
    }
    __syncthreads();                       // B2: hOut ready; sH/sX reads drained

    // ---- 12-15. export h_g, drain, flag, then hist (off critical path) ----
    u64 hv8 = 0ULL;
    if (tid < 64) {
      const int c0 = (tid & 3) * 4;        // 4 f16 = 8B
      hv8 = *(const u64*)(hOut + blw * JW + c0);
      if (ns < TT) {
        u64* hdst = (u64*)(h_g + (((size_t)(ns & 1) * 2 + dir) * NGRP + grp) * BG * HH
                           + blw * HH + slice * JW + c0);
        asm volatile("global_store_dwordx2 %0, %1, off sc1" :: "v"(hdst), "v"(hv8) : "memory");
      }
    }
    if (ns < TT) {
      asm volatile("s_waitcnt vmcnt(0)" ::: "memory");   // h_g stores at L3 before flag
      if (tid == 0)
        __hip_atomic_store(flags + dom * 32 + slice, (unsigned)ns,
                           __ATOMIC_RELAXED, __HIP_MEMORY_SCOPE_AGENT);
    }
    if (tid < 64 && slotBc >= 0) {
      const u64 hvm = mBc > 0.f ? hv8 : 0ULL;            // ys = h * m
      *(u64*)(hist + ((size_t)(dir * BB + gb + blw) * NSLOT + slotBc) * HH
              + slice * JW + (tid & 3) * 4) = hvm;
    }

    // ---- 16. poll packed flag line ----
    if (ns < TT) {
      const unsigned tgt = (unsigned)ns;
      const unsigned* fl = flags + dom * 32 + (lane & 31);
      for (;;) {
        const unsigned v = __hip_atomic_load(fl, __ATOMIC_RELAXED, __HIP_MEMORY_SCOPE_AGENT);
        if (__all((lane >= 32) | (v >= tgt))) break;
        if (--wd < 0) break;
        __builtin_amdgcn_s_sleep(1);
      }
      __builtin_amdgcn_sched_barrier(0);
      asm volatile("" ::: "memory");       // no h_g load hoisting above the poll
    }

    // ---- 17. rotate per-step registers ----
    #pragma unroll
    for (int i = 0; i < 4; ++i) m4c[i] = m4n[i];
    mBc = mBn; slotBc = slotBn;
  }
}

// ---------------- gather boundary outputs ----------------
__global__ __launch_bounds__(256) void gather_out(
    const int* __restrict__ bnd, const int* __restrict__ slotmap,
    const f16* __restrict__ hist, float* __restrict__ out)
{
  const int bw = blockIdx.x;
  const int b = bw >> 6;
  const int w = bw & 63;
  const int k = threadIdx.x * 8;
  const int iv = bnd[b * 65 + w];
  const int jv = bnd[b * 65 + w + 1];
  const bool valid = (iv != -1) && (jv != -1);
  float* dst = out + (size_t)bw * 2048 + k;
  if (valid) {
    const int seg = k >> 9;                    // 0:h_f(i) 1:h_b(i) 2:h_f(j) 3:h_b(j)
    int ts = (seg < 2) ? iv : jv;
    ts = ts < 0 ? 0 : (ts > TT - 1 ? TT - 1 : ts);
    const int dirn = seg & 1;
    const int slot = slotmap[b * TT + ts];
    const f16* src = hist + ((size_t)(dirn * BB + b) * NSLOT + slot) * HH + (k & 511);
    f16x8 v = *(const f16x8*)src;
    float4 o0 = make_float4((float)v[0], (float)v[1], (float)v[2], (float)v[3]);
    float4 o1 = make_float4((float)v[4], (float)v[5], (float)v[6], (float)v[7]);
    *(float4*)dst = o0;
    *(float4*)(dst + 4) = o1;
  } else {
    float4 z = make_float4(0.f, 0.f, 0.f, 0.f);
    *(float4*)dst = z;
    *(float4*)(dst + 4) = z;
  }
}

extern "C" void kernel_launch(void* const* d_in, const int* in_sizes, int n_in,
                              void* d_out, int out_size, void* d_ws, size_t ws_size,
                              hipStream_t stream)
{
  (void)in_sizes; (void)n_in; (void)out_size; (void)ws_size;
  const int* ids     = (const int*)d_in[0];
  const int* maskI   = (const int*)d_in[1];
  const int* bnd     = (const int*)d_in[2];
  const float* emb   = (const float*)d_in[3];
  const float* Wih_f = (const float*)d_in[4];
  const float* Whh_f = (const float*)d_in[5];
  const float* b_f   = (const float*)d_in[6];
  const float* Wih_b = (const float*)d_in[7];
  const float* Whh_b = (const float*)d_in[8];
  const float* b_b   = (const float*)d_in[9];

  char* ws = (char*)d_ws;
  unsigned* flags = (unsigned*)ws;                     // 8*32 packed u32 = 1KB
  int* slotmap    = (int*)(ws + 4096);                 // 128 KiB
  f16* h_g        = (f16*)(ws + 4096 + 131072);        // 256 KiB fp16 ping-pong
  f16* hist       = (f16*)(ws + 4096 + 131072 + 262144);  // ~16.5 MiB

  hipMemsetAsync(flags, 0, 4096, stream);
  build_map<<<dim3(BB), dim3(64), 0, stream>>>(bnd, slotmap);
  lstm_scan<<<dim3(256), dim3(256), 0, stream>>>(ids, maskI, emb,
      Wih_f, Whh_f, b_f, Wih_b, Whh_b, b_b, slotmap, h_g, hist, flags);
  gather_out<<<dim3(BB * 64), dim3(256), 0, stream>>>(bnd, slotmap, hist, (float*)d_out);
}